// Round 3
// baseline (884.343 us; speedup 1.0000x reference)
//
#include <hip/hip_runtime.h>
#include <stdint.h>

#define H_ 16
#define B_ 2
#define S_ 2048
#define DMODEL 1024
#define MTOT 4096

typedef __attribute__((ext_vector_type(8))) __bf16 bf16x8;
typedef __attribute__((ext_vector_type(4))) float f32x4;
typedef unsigned short ushort_t;

typedef __attribute__((address_space(1))) uint32_t u32_g;
typedef __attribute__((address_space(3))) uint32_t u32_l;

static __device__ __forceinline__ unsigned short f2bf(float f) {
  union { float f; uint32_t u; } x; x.f = f;
  uint32_t r = (x.u + 0x7FFFu + ((x.u >> 16) & 1u)) >> 16;
  return (unsigned short)r;
}

static __device__ __forceinline__ void gld_lds16(const void* g, void* l) {
  __builtin_amdgcn_global_load_lds((const u32_g*)g, (u32_l*)l, 16, 0, 0);
}

// ---------------- cast q/k/v fp32 -> bf16 (coalesced float4 in, ushort4 out) ----------------
__global__ __launch_bounds__(256) void cast_qkv(const float* __restrict__ q,
                                                const float* __restrict__ k,
                                                const float* __restrict__ v,
                                                ushort_t* qb, ushort_t* kb, ushort_t* vb) {
  int z = blockIdx.y;
  const float* src = (z == 0) ? q : (z == 1) ? k : v;
  ushort_t* dst = (z == 0) ? qb : (z == 1) ? kb : vb;
  int idx = (blockIdx.x * 256 + threadIdx.x) * 4;
  float4 f = *(const float4*)(src + idx);
  ushort4 o;
  o.x = f2bf(f.x); o.y = f2bf(f.y); o.z = f2bf(f.z); o.w = f2bf(f.w);
  *(ushort4*)(dst + idx) = o;
}

// ---------------- transpose weights fp32 [K][N] -> bf16 [N][K], LDS-tiled 64x64 ----------------
__global__ __launch_bounds__(256) void transw(const float* __restrict__ wq, const float* __restrict__ wk,
                                              const float* __restrict__ wv, const float* __restrict__ wo,
                                              ushort_t* tq, ushort_t* tk, ushort_t* tv, ushort_t* tow) {
  int z = blockIdx.y;
  const float* src = (z == 0) ? wq : (z == 1) ? wk : (z == 2) ? wv : wo;
  ushort_t* dst = (z == 0) ? tq : (z == 1) ? tk : (z == 2) ? tv : tow;
  __shared__ ushort_t lds[64 * 65];
  int t = threadIdx.x;
  int k0 = (blockIdx.x & 15) * 64;
  int n0 = (blockIdx.x >> 4) * 64;
  int r = t >> 4;          // 0..15
  int c4 = (t & 15) * 4;   // n-col within tile
#pragma unroll
  for (int j = 0; j < 4; ++j) {
    int row = j * 16 + r;  // k within tile
    float4 f = *(const float4*)(src + (size_t)(k0 + row) * DMODEL + n0 + c4);
    lds[(c4 + 0) * 65 + row] = f2bf(f.x);
    lds[(c4 + 1) * 65 + row] = f2bf(f.y);
    lds[(c4 + 2) * 65 + row] = f2bf(f.z);
    lds[(c4 + 3) * 65 + row] = f2bf(f.w);
  }
  __syncthreads();
  int nn = t >> 2;          // 0..63 (n within tile)
  int kb = (t & 3) * 16;    // k group
  ushort_t tmp[16];
#pragma unroll
  for (int j = 0; j < 16; ++j) tmp[j] = lds[nn * 65 + kb + j];
  ushort_t* dp = dst + (size_t)(n0 + nn) * DMODEL + k0 + kb;
  *(uint4*)(dp + 0) = *(const uint4*)(tmp + 0);
  *(uint4*)(dp + 8) = *(const uint4*)(tmp + 8);
}

// ---------------- GEMM: [4096x1024] x [1024x1024], A bf16 row-major, Bt bf16 [N][K] ----------------
struct GemmArgs {
  const ushort_t* A;
  const ushort_t* Bt;
  const float* bias;
  void* out;
  int mode;     // 0: bf16 out [B][H][S][64]; 1: bf16 out [B][H][64][S] (LDS-transposed epilogue); 2: fp32 out [M][N]
  float mult;
};

__global__ __launch_bounds__(256) void gemm128(GemmArgs g0, GemmArgs g1, GemmArgs g2) {
  GemmArgs ga = (blockIdx.z == 0) ? g0 : (blockIdx.z == 1) ? g1 : g2;
  __shared__ alignas(16) ushort_t smem[2][128 * 64];   // As, Bs; reused as [128][128] in mode-1 epilogue
  ushort_t* As = smem[0];
  ushort_t* Bs = smem[1];
  int tid = threadIdx.x, wid = tid >> 6, lane = tid & 63;
  int lg = lane >> 4, li = lane & 15;
  int wr = wid >> 1, wc = wid & 1;
  int m0 = blockIdx.y * 128, n0 = blockIdx.x * 128;
  f32x4 acc[4][4] = {};
  const ushort_t* Ab = ga.A + (size_t)m0 * DMODEL;
  const ushort_t* Bb = ga.Bt + (size_t)n0 * DMODEL;

  for (int kt = 0; kt < DMODEL / 64; ++kt) {
    int k0 = kt * 64;
    __syncthreads();
#pragma unroll
    for (int r = 0; r < 4; ++r) {
      int c = r * 256 + tid;
      int row = c >> 3, off = (c & 7) * 8;
      gld_lds16(Ab + row * DMODEL + k0 + off, (char*)As + c * 16);
      gld_lds16(Bb + row * DMODEL + k0 + off, (char*)Bs + c * 16);
    }
    __syncthreads();
#pragma unroll
    for (int kk = 0; kk < 2; ++kk) {
      bf16x8 af[4], bfr[4];
#pragma unroll
      for (int x = 0; x < 4; ++x) {
        af[x]  = *(const bf16x8*)(As + (wr * 64 + x * 16 + li) * 64 + kk * 32 + lg * 8);
        bfr[x] = *(const bf16x8*)(Bs + (wc * 64 + x * 16 + li) * 64 + kk * 32 + lg * 8);
      }
#pragma unroll
      for (int mi = 0; mi < 4; ++mi)
#pragma unroll
        for (int ni = 0; ni < 4; ++ni)
          acc[mi][ni] = __builtin_amdgcn_mfma_f32_16x16x32_bf16(af[mi], bfr[ni], acc[mi][ni], 0, 0, 0);
    }
  }

  // D mapping (verified): col = lane&15, row = (lane>>4)*4 + reg
  if (ga.mode == 1) {
    // V-transposed output: route through LDS so global stores are 16B coalesced.
    __syncthreads();
    ushort_t* ep = &smem[0][0];   // [128 n][128 m] spans both halves (32 KB)
#pragma unroll
    for (int mi = 0; mi < 4; ++mi)
#pragma unroll
      for (int ni = 0; ni < 4; ++ni) {
        int nl = wc * 64 + ni * 16 + li;
        float bv = ga.bias[n0 + nl];
#pragma unroll
        for (int i = 0; i < 4; ++i) {
          int ml = wr * 64 + mi * 16 + lg * 4 + i;
          ep[nl * 128 + ml] = f2bf((acc[mi][ni][i] + bv) * ga.mult);
        }
      }
    __syncthreads();
    int row = tid >> 1;           // n_local 0..127
    int cg  = (tid & 1) * 64;     // m_local base
    int n = n0 + row;
    int h = n >> 6, d = n & 63;
    int b = m0 >> 11;
    size_t base = ((size_t)(b * H_ + h) * 64 + d) * S_ + (m0 & 2047) + cg;
    ushort_t* out = (ushort_t*)ga.out;
    const ushort_t* sp = ep + row * 128 + cg;
#pragma unroll
    for (int j = 0; j < 8; ++j)
      *(uint4*)(out + base + j * 8) = *(const uint4*)(sp + j * 8);
  } else {
#pragma unroll
    for (int mi = 0; mi < 4; ++mi) {
#pragma unroll
      for (int ni = 0; ni < 4; ++ni) {
        int n = n0 + wc * 64 + ni * 16 + li;
        float bv = ga.bias[n];
#pragma unroll
        for (int i = 0; i < 4; ++i) {
          int m = m0 + wr * 64 + mi * 16 + lg * 4 + i;
          float val = (acc[mi][ni][i] + bv) * ga.mult;
          if (ga.mode == 2) {
            ((float*)ga.out)[(size_t)m * DMODEL + n] = val;
          } else {
            int b = m >> 11, s = m & 2047;
            int h = n >> 6, d = n & 63;
            size_t addr = ((size_t)(b * H_ + h) * S_ + s) * 64 + d;
            ((ushort_t*)ga.out)[addr] = f2bf(val);
          }
        }
      }
    }
  }
}

// ---------------- fused flash attention, 2-phase pipelined ----------------
// grid: (S/64, H, B), 256 threads, 4 blocks/CU (40KB LDS). Wave w owns q-rows [qt+16w, +16).
// Pipeline: at iter t the barrier drains {stage(t), bias(t)} issued during iter t-1;
// then stage(t+1)+bias(t+1) are issued BEFORE tile-t compute (T3 2-phase / T14-lite).
__global__ __launch_bounds__(256, 4) void attn(const ushort_t* __restrict__ Qh,
                                               const ushort_t* __restrict__ Kh,
                                               const ushort_t* __restrict__ VhT,
                                               const float* __restrict__ bias,
                                               ushort_t* __restrict__ attnO) {
  int qt = blockIdx.x * 64;
  int h = blockIdx.y, b = blockIdx.z;
  int tid = threadIdx.x, wid = tid >> 6, lane = tid & 63;
  int lg = lane >> 4, li = lane & 15;
  __shared__ alignas(16) ushort_t Ks[2][64 * 64];
  __shared__ alignas(16) ushort_t Vts[2][64 * 64];
  __shared__ alignas(16) ushort_t Ps[4][16][64];

  const size_t bh = (size_t)(b * H_ + h);
  const ushort_t* Qbase = Qh + bh * S_ * 64;
  const ushort_t* Kbase = Kh + bh * S_ * 64;
  const ushort_t* Vbase = VhT + bh * 64 * S_;
  const float* biasb = bias + bh * (size_t)S_ * S_;
  const int qrow = qt + wid * 16 + lg * 4;

  // Q fragments hoisted to registers (A-operand: row=li, k=lg*8+j, two k-halves)
  bf16x8 qf[2];
#pragma unroll
  for (int kk = 0; kk < 2; ++kk)
    qf[kk] = *(const bf16x8*)(Qbase + (size_t)(qt + wid * 16 + li) * 64 + kk * 32 + lg * 8);

  auto stage = [&](int buf, int t) {
#pragma unroll
    for (int r = 0; r < 2; ++r) {
      int cc = r * 256 + tid;
      int row = cc >> 3, off = (cc & 7) * 8;
      gld_lds16(Kbase + (size_t)(t * 64 + row) * 64 + off, (char*)Ks[buf] + cc * 16);
      gld_lds16(Vbase + (size_t)row * S_ + t * 64 + off, (char*)Vts[buf] + cc * 16);
    }
  };
  auto biasld = [&](float (&dst)[4][4], int t) {
#pragma unroll
    for (int n = 0; n < 4; ++n)
#pragma unroll
      for (int i = 0; i < 4; ++i)
        dst[n][i] = biasb[(size_t)(qrow + i) * S_ + t * 64 + n * 16 + li];
  };

  f32x4 o[4] = {};
  float mrow[4] = {-3.0e38f, -3.0e38f, -3.0e38f, -3.0e38f};
  float lrow[4] = {0.f, 0.f, 0.f, 0.f};
  float bsvN[4][4], bsvC[4][4];

  stage(0, 0);
  biasld(bsvN, 0);

  for (int t = 0; t < S_ / 64; ++t) {
    __syncthreads();   // drains stage(t)+bias(t) vmem; protects LDS buffer reuse
#pragma unroll
    for (int n = 0; n < 4; ++n)
#pragma unroll
      for (int i = 0; i < 4; ++i)
        bsvC[n][i] = bsvN[n][i];
    if (t + 1 < S_ / 64) {
      stage((t + 1) & 1, t + 1);     // in flight across tile-t compute
      biasld(bsvN, t + 1);
    }
    const ushort_t* Kc = Ks[t & 1];
    const ushort_t* Vc = Vts[t & 1];

    // S = Q K^T  (Q pre-scaled by 1/8)
    f32x4 sc[4] = {};
#pragma unroll
    for (int kk = 0; kk < 2; ++kk) {
#pragma unroll
      for (int n = 0; n < 4; ++n) {
        bf16x8 bk = *(const bf16x8*)(Kc + (n * 16 + li) * 64 + kk * 32 + lg * 8);
        sc[n] = __builtin_amdgcn_mfma_f32_16x16x32_bf16(qf[kk], bk, sc[n], 0, 0, 0);
      }
    }
#pragma unroll
    for (int n = 0; n < 4; ++n)
#pragma unroll
      for (int i = 0; i < 4; ++i)
        sc[n][i] += bsvC[n][i];

    // online softmax: row (lg*4+i) lives in the 16 lanes sharing lg
    float p[4][4];
#pragma unroll
    for (int i = 0; i < 4; ++i) {
      float tm = fmaxf(fmaxf(sc[0][i], sc[1][i]), fmaxf(sc[2][i], sc[3][i]));
#pragma unroll
      for (int w = 1; w < 16; w <<= 1) tm = fmaxf(tm, __shfl_xor(tm, w));
      float mn = fmaxf(mrow[i], tm);
      float alpha = __expf(mrow[i] - mn);
      float rs = 0.f;
#pragma unroll
      for (int n = 0; n < 4; ++n) { p[n][i] = __expf(sc[n][i] - mn); rs += p[n][i]; }
#pragma unroll
      for (int w = 1; w < 16; w <<= 1) rs += __shfl_xor(rs, w);
      lrow[i] = lrow[i] * alpha + rs;
      mrow[i] = mn;
#pragma unroll
      for (int n = 0; n < 4; ++n) o[n][i] *= alpha;
    }

    // P (D-layout) -> LDS -> (A-layout); Ps[wid] is wave-private, no barrier needed
#pragma unroll
    for (int n = 0; n < 4; ++n)
#pragma unroll
      for (int i = 0; i < 4; ++i)
        Ps[wid][lg * 4 + i][n * 16 + li] = f2bf(p[n][i]);

    // O += P V
#pragma unroll
    for (int kk = 0; kk < 2; ++kk) {
      bf16x8 pa = *(const bf16x8*)(&Ps[wid][li][kk * 32 + lg * 8]);
#pragma unroll
      for (int n = 0; n < 4; ++n) {
        bf16x8 bv = *(const bf16x8*)(Vc + (n * 16 + li) * 64 + kk * 32 + lg * 8);
        o[n] = __builtin_amdgcn_mfma_f32_16x16x32_bf16(pa, bv, o[n], 0, 0, 0);
      }
    }
  }

  float rinv[4];
#pragma unroll
  for (int i = 0; i < 4; ++i) rinv[i] = 1.0f / lrow[i];
#pragma unroll
  for (int n = 0; n < 4; ++n)
#pragma unroll
    for (int i = 0; i < 4; ++i) {
      int q = qt + wid * 16 + lg * 4 + i;
      int col = h * 64 + n * 16 + li;
      attnO[(size_t)(b * S_ + q) * DMODEL + col] = f2bf(o[n][i] * rinv[i]);
    }
}

extern "C" void kernel_launch(void* const* d_in, const int* in_sizes, int n_in,
                              void* d_out, int out_size, void* d_ws, size_t ws_size,
                              hipStream_t stream) {
  const float* q    = (const float*)d_in[0];
  const float* k    = (const float*)d_in[1];
  const float* v    = (const float*)d_in[2];
  const float* bias = (const float*)d_in[3];
  const float* w_q  = (const float*)d_in[4];
  const float* b_q  = (const float*)d_in[5];
  const float* w_k  = (const float*)d_in[6];
  const float* b_k  = (const float*)d_in[7];
  const float* w_v  = (const float*)d_in[8];
  const float* b_v  = (const float*)d_in[9];
  const float* w_o  = (const float*)d_in[10];
  const float* b_o  = (const float*)d_in[11];

  char* ws = (char*)d_ws;
  const size_t MB = 1ull << 20;
  ushort_t* qb  = (ushort_t*)(ws + 0 * MB);    // dead after gemm z=0 -> reused for aO
  ushort_t* kb  = (ushort_t*)(ws + 8 * MB);
  ushort_t* vb  = (ushort_t*)(ws + 16 * MB);
  ushort_t* wqT = (ushort_t*)(ws + 24 * MB);
  ushort_t* wkT = (ushort_t*)(ws + 26 * MB);
  ushort_t* wvT = (ushort_t*)(ws + 28 * MB);
  ushort_t* woT = (ushort_t*)(ws + 30 * MB);
  ushort_t* Qh  = (ushort_t*)(ws + 32 * MB);
  ushort_t* Kh  = (ushort_t*)(ws + 40 * MB);
  ushort_t* VhT = (ushort_t*)(ws + 48 * MB);
  ushort_t* aO  = qb;                           // alias: qb dead once attn runs

  cast_qkv<<<dim3(4096, 3, 1), 256, 0, stream>>>(q, k, v, qb, kb, vb);
  transw<<<dim3(256, 4, 1), 256, 0, stream>>>(w_q, w_k, w_v, w_o, wqT, wkT, wvT, woT);

  GemmArgs gq { qb, wqT, b_q, (void*)Qh,  0, 0.125f };  // 1/sqrt(64) folded into Q
  GemmArgs gk { kb, wkT, b_k, (void*)Kh,  0, 1.0f };
  GemmArgs gv { vb, wvT, b_v, (void*)VhT, 1, 1.0f };
  gemm128<<<dim3(8, 32, 3), 256, 0, stream>>>(gq, gk, gv);

  attn<<<dim3(32, 16, 2), 256, 0, stream>>>(Qh, Kh, VhT, bias, aO);

  GemmArgs go { aO, woT, b_o, d_out, 2, 1.0f };
  gemm128<<<dim3(8, 32, 1), 256, 0, stream>>>(go, go, go);
}

// Round 11
// 881.884 us; speedup vs baseline: 1.0028x; 1.0028x over previous
//
#include <hip/hip_runtime.h>
#include <stdint.h>

#define H_ 16
#define B_ 2
#define S_ 2048
#define DMODEL 1024
#define MTOT 4096

typedef __attribute__((ext_vector_type(8))) __bf16 bf16x8;
typedef __attribute__((ext_vector_type(4))) float f32x4;
typedef unsigned short ushort_t;

typedef __attribute__((address_space(1))) uint32_t u32_g;
typedef __attribute__((address_space(3))) uint32_t u32_l;

static __device__ __forceinline__ unsigned short f2bf(float f) {
  union { float f; uint32_t u; } x; x.f = f;
  uint32_t r = (x.u + 0x7FFFu + ((x.u >> 16) & 1u)) >> 16;
  return (unsigned short)r;
}

static __device__ __forceinline__ void gld_lds16(const void* g, void* l) {
  __builtin_amdgcn_global_load_lds((const u32_g*)g, (u32_l*)l, 16, 0, 0);
}

// ---------------- cast q/k/v fp32 -> bf16 ----------------
__global__ __launch_bounds__(256) void cast_qkv(const float* __restrict__ q,
                                                const float* __restrict__ k,
                                                const float* __restrict__ v,
                                                ushort_t* qb, ushort_t* kb, ushort_t* vb) {
  int z = blockIdx.y;
  const float* src = (z == 0) ? q : (z == 1) ? k : v;
  ushort_t* dst = (z == 0) ? qb : (z == 1) ? kb : vb;
  int idx = (blockIdx.x * 256 + threadIdx.x) * 4;
  float4 f = *(const float4*)(src + idx);
  ushort4 o;
  o.x = f2bf(f.x); o.y = f2bf(f.y); o.z = f2bf(f.z); o.w = f2bf(f.w);
  *(ushort4*)(dst + idx) = o;
}

// ---------------- transpose weights fp32 [K][N] -> bf16 [N][K], LDS-tiled 64x64 ----------------
__global__ __launch_bounds__(256) void transw(const float* __restrict__ wq, const float* __restrict__ wk,
                                              const float* __restrict__ wv, const float* __restrict__ wo,
                                              ushort_t* tq, ushort_t* tk, ushort_t* tv, ushort_t* tow) {
  int z = blockIdx.y;
  const float* src = (z == 0) ? wq : (z == 1) ? wk : (z == 2) ? wv : wo;
  ushort_t* dst = (z == 0) ? tq : (z == 1) ? tk : (z == 2) ? tv : tow;
  __shared__ ushort_t lds[64 * 65];
  int t = threadIdx.x;
  int k0 = (blockIdx.x & 15) * 64;
  int n0 = (blockIdx.x >> 4) * 64;
  int r = t >> 4;
  int c4 = (t & 15) * 4;
#pragma unroll
  for (int j = 0; j < 4; ++j) {
    int row = j * 16 + r;
    float4 f = *(const float4*)(src + (size_t)(k0 + row) * DMODEL + n0 + c4);
    lds[(c4 + 0) * 65 + row] = f2bf(f.x);
    lds[(c4 + 1) * 65 + row] = f2bf(f.y);
    lds[(c4 + 2) * 65 + row] = f2bf(f.z);
    lds[(c4 + 3) * 65 + row] = f2bf(f.w);
  }
  __syncthreads();
  int nn = t >> 2;
  int kb = (t & 3) * 16;
  ushort_t tmp[16];
#pragma unroll
  for (int j = 0; j < 16; ++j) tmp[j] = lds[nn * 65 + kb + j];
  ushort_t* dp = dst + (size_t)(n0 + nn) * DMODEL + k0 + kb;
  *(uint4*)(dp + 0) = *(const uint4*)(tmp + 0);
  *(uint4*)(dp + 8) = *(const uint4*)(tmp + 8);
}

// ---------------- GEMM 128x128: QKV projections ----------------
struct GemmArgs {
  const ushort_t* A;
  const ushort_t* Bt;
  const float* bias;
  void* out;
  int mode;     // 0: bf16 out [B][H][S][64]; 1: bf16 out [B][H][64][S]
  float mult;
};

__global__ __launch_bounds__(256) void gemm128(GemmArgs g0, GemmArgs g1, GemmArgs g2) {
  GemmArgs ga = (blockIdx.z == 0) ? g0 : (blockIdx.z == 1) ? g1 : g2;
  __shared__ alignas(16) ushort_t smem[2][128 * 64];
  ushort_t* As = smem[0];
  ushort_t* Bs = smem[1];
  int tid = threadIdx.x, wid = tid >> 6, lane = tid & 63;
  int lg = lane >> 4, li = lane & 15;
  int wr = wid >> 1, wc = wid & 1;
  int m0 = blockIdx.y * 128, n0 = blockIdx.x * 128;
  f32x4 acc[4][4] = {};
  const ushort_t* Ab = ga.A + (size_t)m0 * DMODEL;
  const ushort_t* Bb = ga.Bt + (size_t)n0 * DMODEL;

  for (int kt = 0; kt < DMODEL / 64; ++kt) {
    int k0 = kt * 64;
    __syncthreads();
#pragma unroll
    for (int r = 0; r < 4; ++r) {
      int c = r * 256 + tid;
      int row = c >> 3, off = (c & 7) * 8;
      gld_lds16(Ab + row * DMODEL + k0 + off, (char*)As + c * 16);
      gld_lds16(Bb + row * DMODEL + k0 + off, (char*)Bs + c * 16);
    }
    __syncthreads();
#pragma unroll
    for (int kk = 0; kk < 2; ++kk) {
      bf16x8 af[4], bfr[4];
#pragma unroll
      for (int x = 0; x < 4; ++x) {
        af[x]  = *(const bf16x8*)(As + (wr * 64 + x * 16 + li) * 64 + kk * 32 + lg * 8);
        bfr[x] = *(const bf16x8*)(Bs + (wc * 64 + x * 16 + li) * 64 + kk * 32 + lg * 8);
      }
#pragma unroll
      for (int mi = 0; mi < 4; ++mi)
#pragma unroll
        for (int ni = 0; ni < 4; ++ni)
          acc[mi][ni] = __builtin_amdgcn_mfma_f32_16x16x32_bf16(af[mi], bfr[ni], acc[mi][ni], 0, 0, 0);
    }
  }

  // D mapping (verified): col = lane&15, row = (lane>>4)*4 + reg
  if (ga.mode == 1) {
    __syncthreads();
    ushort_t* ep = &smem[0][0];   // [128 n][128 m] spans both halves
#pragma unroll
    for (int mi = 0; mi < 4; ++mi)
#pragma unroll
      for (int ni = 0; ni < 4; ++ni) {
        int nl = wc * 64 + ni * 16 + li;
        float bv = ga.bias[n0 + nl];
#pragma unroll
        for (int i = 0; i < 4; ++i) {
          int ml = wr * 64 + mi * 16 + lg * 4 + i;
          ep[nl * 128 + ml] = f2bf((acc[mi][ni][i] + bv) * ga.mult);
        }
      }
    __syncthreads();
    int row = tid >> 1;
    int cg  = (tid & 1) * 64;
    int n = n0 + row;
    int h = n >> 6, d = n & 63;
    int b = m0 >> 11;
    size_t base = ((size_t)(b * H_ + h) * 64 + d) * S_ + (m0 & 2047) + cg;
    ushort_t* out = (ushort_t*)ga.out;
    const ushort_t* sp = ep + row * 128 + cg;
#pragma unroll
    for (int j = 0; j < 8; ++j)
      *(uint4*)(out + base + j * 8) = *(const uint4*)(sp + j * 8);
  } else {
#pragma unroll
    for (int mi = 0; mi < 4; ++mi) {
#pragma unroll
      for (int ni = 0; ni < 4; ++ni) {
        int n = n0 + wc * 64 + ni * 16 + li;
        float bv = ga.bias[n];
#pragma unroll
        for (int i = 0; i < 4; ++i) {
          int m = m0 + wr * 64 + mi * 16 + lg * 4 + i;
          float val = (acc[mi][ni][i] + bv) * ga.mult;
          int b = m >> 11, s = m & 2047;
          int h = n >> 6, d = n & 63;
          size_t addr = ((size_t)(b * H_ + h) * S_ + s) * 64 + d;
          ((ushort_t*)ga.out)[addr] = f2bf(val);
        }
      }
    }
  }
}

// ---------------- GEMM 64x128: output projection (512 blocks = 2/CU for latency hiding) ----------------
__global__ __launch_bounds__(256) void gemm_out(const ushort_t* __restrict__ A,
                                                const ushort_t* __restrict__ Bt,
                                                const float* __restrict__ bias,
                                                float* __restrict__ out) {
  __shared__ alignas(16) ushort_t As[64 * 64];
  __shared__ alignas(16) ushort_t Bs[128 * 64];
  int tid = threadIdx.x, wid = tid >> 6, lane = tid & 63;
  int lg = lane >> 4, li = lane & 15;
  int m0 = blockIdx.y * 64, n0 = blockIdx.x * 128;
  f32x4 acc[4][2] = {};
  const ushort_t* Ab = A + (size_t)m0 * DMODEL;
  const ushort_t* Bb = Bt + (size_t)n0 * DMODEL;

  for (int kt = 0; kt < DMODEL / 64; ++kt) {
    int k0 = kt * 64;
    __syncthreads();
#pragma unroll
    for (int r = 0; r < 2; ++r) {
      int c = r * 256 + tid;
      int row = c >> 3, off = (c & 7) * 8;
      gld_lds16(Ab + row * DMODEL + k0 + off, (char*)As + c * 16);
    }
#pragma unroll
    for (int r = 0; r < 4; ++r) {
      int c = r * 256 + tid;
      int row = c >> 3, off = (c & 7) * 8;
      gld_lds16(Bb + row * DMODEL + k0 + off, (char*)Bs + c * 16);
    }
    __syncthreads();
#pragma unroll
    for (int kk = 0; kk < 2; ++kk) {
      bf16x8 af[4], bfr[2];
#pragma unroll
      for (int x = 0; x < 4; ++x)
        af[x] = *(const bf16x8*)(As + (x * 16 + li) * 64 + kk * 32 + lg * 8);
#pragma unroll
      for (int x = 0; x < 2; ++x)
        bfr[x] = *(const bf16x8*)(Bs + (wid * 32 + x * 16 + li) * 64 + kk * 32 + lg * 8);
#pragma unroll
      for (int mi = 0; mi < 4; ++mi)
#pragma unroll
        for (int ni = 0; ni < 2; ++ni)
          acc[mi][ni] = __builtin_amdgcn_mfma_f32_16x16x32_bf16(af[mi], bfr[ni], acc[mi][ni], 0, 0, 0);
    }
  }
#pragma unroll
  for (int mi = 0; mi < 4; ++mi)
#pragma unroll
    for (int ni = 0; ni < 2; ++ni) {
      int n = n0 + wid * 32 + ni * 16 + li;
      float bv = bias[n];
#pragma unroll
      for (int i = 0; i < 4; ++i) {
        int m = m0 + mi * 16 + lg * 4 + i;
        out[(size_t)m * DMODEL + n] = acc[mi][ni][i] + bv;
      }
    }
}

// ---------------- fused flash attention, 2-phase pipelined + LDS XOR-swizzle (T2) ----------------
// K/V staged via global_load_lds with PRE-SWIZZLED GLOBAL SOURCE (linear LDS dest, rule 21):
// within each 128B row, 16B chunk c8 holds global chunk c8^(row&7). Reads XOR the same way.
// This breaks the 16-way row-major bank conflict (all li-lanes at row*128B -> bank quad 0).
__global__ __launch_bounds__(256, 4) void attn(const ushort_t* __restrict__ Qh,
                                               const ushort_t* __restrict__ Kh,
                                               const ushort_t* __restrict__ VhT,
                                               const float* __restrict__ bias,
                                               ushort_t* __restrict__ attnO) {
  int qt = blockIdx.x * 64;
  int h = blockIdx.y, b = blockIdx.z;
  int tid = threadIdx.x, wid = tid >> 6, lane = tid & 63;
  int lg = lane >> 4, li = lane & 15;
  __shared__ alignas(16) ushort_t Ks[2][64 * 64];
  __shared__ alignas(16) ushort_t Vts[2][64 * 64];
  __shared__ alignas(16) ushort_t Ps[4 * 16 * 64];

  const size_t bh = (size_t)(b * H_ + h);
  const ushort_t* Qbase = Qh + bh * S_ * 64;
  const ushort_t* Kbase = Kh + bh * S_ * 64;
  const ushort_t* Vbase = VhT + bh * 64 * S_;
  const float* biasb = bias + bh * (size_t)S_ * S_;
  const int qrow = qt + wid * 16 + lg * 4;

  bf16x8 qf[2];
#pragma unroll
  for (int kk = 0; kk < 2; ++kk)
    qf[kk] = *(const bf16x8*)(Qbase + (size_t)(qt + wid * 16 + li) * 64 + kk * 32 + lg * 8);

  auto stage = [&](int buf, int t) {
#pragma unroll
    for (int r = 0; r < 2; ++r) {
      int cc = r * 256 + tid;
      int row = cc >> 3;
      int off = ((cc & 7) ^ (row & 7)) * 8;   // pre-swizzled source (stays in same 128B row)
      gld_lds16(Kbase + (size_t)(t * 64 + row) * 64 + off, (char*)Ks[buf] + cc * 16);
      gld_lds16(Vbase + (size_t)row * S_ + t * 64 + off, (char*)Vts[buf] + cc * 16);
    }
  };
  auto biasld = [&](float (&dst)[4][4], int t) {
#pragma unroll
    for (int n = 0; n < 4; ++n)
#pragma unroll
      for (int i = 0; i < 4; ++i)
        dst[n][i] = biasb[(size_t)(qrow + i) * S_ + t * 64 + n * 16 + li];
  };

  f32x4 o[4] = {};
  float mrow[4] = {-3.0e38f, -3.0e38f, -3.0e38f, -3.0e38f};
  float lrow[4] = {0.f, 0.f, 0.f, 0.f};
  float bsvN[4][4], bsvC[4][4];

  stage(0, 0);
  biasld(bsvN, 0);

  for (int t = 0; t < S_ / 64; ++t) {
    __syncthreads();   // drains stage(t)+bias(t); protects LDS buffer reuse
#pragma unroll
    for (int n = 0; n < 4; ++n)
#pragma unroll
      for (int i = 0; i < 4; ++i)
        bsvC[n][i] = bsvN[n][i];
    if (t + 1 < S_ / 64) {
      stage((t + 1) & 1, t + 1);     // in flight across tile-t compute
      biasld(bsvN, t + 1);
    }
    const ushort_t* Kc = Ks[t & 1];
    const ushort_t* Vc = Vts[t & 1];

    // S = Q K^T  (Q pre-scaled by 1/8); swizzled B-fragment reads
    f32x4 sc[4] = {};
#pragma unroll
    for (int kk = 0; kk < 2; ++kk) {
#pragma unroll
      for (int n = 0; n < 4; ++n) {
        int c8 = (kk * 4 + lg) ^ (li & 7);
        bf16x8 bk = *(const bf16x8*)(Kc + (n * 16 + li) * 64 + c8 * 8);
        sc[n] = __builtin_amdgcn_mfma_f32_16x16x32_bf16(qf[kk], bk, sc[n], 0, 0, 0);
      }
    }
#pragma unroll
    for (int n = 0; n < 4; ++n)
#pragma unroll
      for (int i = 0; i < 4; ++i)
        sc[n][i] += bsvC[n][i];

    // online softmax: row (lg*4+i) lives in the 16 lanes sharing lg
    float p[4][4];
#pragma unroll
    for (int i = 0; i < 4; ++i) {
      float tm = fmaxf(fmaxf(sc[0][i], sc[1][i]), fmaxf(sc[2][i], sc[3][i]));
#pragma unroll
      for (int w = 1; w < 16; w <<= 1) tm = fmaxf(tm, __shfl_xor(tm, w));
      float mn = fmaxf(mrow[i], tm);
      float alpha = __expf(mrow[i] - mn);
      float rs = 0.f;
#pragma unroll
      for (int n = 0; n < 4; ++n) { p[n][i] = __expf(sc[n][i] - mn); rs += p[n][i]; }
#pragma unroll
      for (int w = 1; w < 16; w <<= 1) rs += __shfl_xor(rs, w);
      lrow[i] = lrow[i] * alpha + rs;
      mrow[i] = mn;
#pragma unroll
      for (int n = 0; n < 4; ++n) o[n][i] *= alpha;
    }

    // P (D-layout) -> LDS (swizzled) -> (A-layout); Ps[wid] wave-private
#pragma unroll
    for (int n = 0; n < 4; ++n)
#pragma unroll
      for (int i = 0; i < 4; ++i) {
        int r = lg * 4 + i;
        int c8s = (n * 2 + (li >> 3)) ^ (r & 7);
        Ps[wid * 1024 + r * 64 + c8s * 8 + (li & 7)] = f2bf(p[n][i]);
      }

    // O += P V (swizzled A- and B-fragment reads)
#pragma unroll
    for (int kk = 0; kk < 2; ++kk) {
      int c8p = (kk * 4 + lg) ^ (li & 7);
      bf16x8 pa = *(const bf16x8*)(Ps + wid * 1024 + li * 64 + c8p * 8);
#pragma unroll
      for (int n = 0; n < 4; ++n) {
        int c8 = (kk * 4 + lg) ^ (li & 7);
        bf16x8 bv = *(const bf16x8*)(Vc + (n * 16 + li) * 64 + c8 * 8);
        o[n] = __builtin_amdgcn_mfma_f32_16x16x32_bf16(pa, bv, o[n], 0, 0, 0);
      }
    }
  }

  float rinv[4];
#pragma unroll
  for (int i = 0; i < 4; ++i) rinv[i] = 1.0f / lrow[i];
#pragma unroll
  for (int n = 0; n < 4; ++n)
#pragma unroll
    for (int i = 0; i < 4; ++i) {
      int q = qt + wid * 16 + lg * 4 + i;
      int col = h * 64 + n * 16 + li;
      attnO[(size_t)(b * S_ + q) * DMODEL + col] = f2bf(o[n][i] * rinv[i]);
    }
}

extern "C" void kernel_launch(void* const* d_in, const int* in_sizes, int n_in,
                              void* d_out, int out_size, void* d_ws, size_t ws_size,
                              hipStream_t stream) {
  const float* q    = (const float*)d_in[0];
  const float* k    = (const float*)d_in[1];
  const float* v    = (const float*)d_in[2];
  const float* bias = (const float*)d_in[3];
  const float* w_q  = (const float*)d_in[4];
  const float* b_q  = (const float*)d_in[5];
  const float* w_k  = (const float*)d_in[6];
  const float* b_k  = (const float*)d_in[7];
  const float* w_v  = (const float*)d_in[8];
  const float* b_v  = (const float*)d_in[9];
  const float* w_o  = (const float*)d_in[10];
  const float* b_o  = (const float*)d_in[11];

  char* ws = (char*)d_ws;
  const size_t MB = 1ull << 20;
  ushort_t* qb  = (ushort_t*)(ws + 0 * MB);    // dead after gemm z=0 -> reused for aO
  ushort_t* kb  = (ushort_t*)(ws + 8 * MB);
  ushort_t* vb  = (ushort_t*)(ws + 16 * MB);
  ushort_t* wqT = (ushort_t*)(ws + 24 * MB);
  ushort_t* wkT = (ushort_t*)(ws + 26 * MB);
  ushort_t* wvT = (ushort_t*)(ws + 28 * MB);
  ushort_t* woT = (ushort_t*)(ws + 30 * MB);
  ushort_t* Qh  = (ushort_t*)(ws + 32 * MB);
  ushort_t* Kh  = (ushort_t*)(ws + 40 * MB);
  ushort_t* VhT = (ushort_t*)(ws + 48 * MB);
  ushort_t* aO  = qb;                           // alias: qb dead once attn runs

  cast_qkv<<<dim3(4096, 3, 1), 256, 0, stream>>>(q, k, v, qb, kb, vb);
  transw<<<dim3(256, 4, 1), 256, 0, stream>>>(w_q, w_k, w_v, w_o, wqT, wkT, wvT, woT);

  GemmArgs gq { qb, wqT, b_q, (void*)Qh,  0, 0.125f };  // 1/sqrt(64) folded into Q
  GemmArgs gk { kb, wkT, b_k, (void*)Kh,  0, 1.0f };
  GemmArgs gv { vb, wvT, b_v, (void*)VhT, 1, 1.0f };
  gemm128<<<dim3(8, 32, 3), 256, 0, stream>>>(gq, gk, gv);

  attn<<<dim3(32, 16, 2), 256, 0, stream>>>(Qh, Kh, VhT, bias, aO);

  gemm_out<<<dim3(8, 64, 1), 256, 0, stream>>>(aO, woT, b_o, (float*)d_out);
}